// Round 3
// baseline (693.069 us; speedup 1.0000x reference)
//
#include <hip/hip_runtime.h>

#define NVOX (256*256*32)   // 2,097,152
#define CC 64
#define HH 480
#define WW 640
#define HWTOT (HH*WW)        // 307,200 pixels

#define SLICES 8             // channel slices
#define CPS 8                // channels per slice; slice table = HWTOT*8*2B = 4.9 MB ~ L2

typedef float vfloat4 __attribute__((ext_vector_type(4)));
typedef int   vint4   __attribute__((ext_vector_type(4)));
typedef int   vint2   __attribute__((ext_vector_type(2)));
typedef _Float16 f16x4 __attribute__((ext_vector_type(4)));
typedef _Float16 f16x8 __attribute__((ext_vector_type(8)));

// ---------------- Kernel 1: per-voxel weight + feat index, packed (fi, w) 8B ------------
__global__ __launch_bounds__(256) void weight_kernel(
    const int*   __restrict__ pp,      // (N,2)
    const int*   __restrict__ scale_p, // scalar
    const int*   __restrict__ mask,    // (N,)
    const float* __restrict__ pix_z,   // (N,)
    const float* __restrict__ depth,   // (H*W,) f32, L2-resident (1.2MB)
    vint2*       __restrict__ meta)    // (N,) {fi, bits(w)}
{
    int i = blockIdx.x * blockDim.x + threadIdx.x;
    int scale = scale_p[0];

    vint2 p2 = __builtin_nontemporal_load((const vint2*)pp + i);
    int   m  = __builtin_nontemporal_load(mask + i);
    float z  = __builtin_nontemporal_load(pix_z + i);

    int px = p2.x, py = p2.y;
    int sx = px, sy = py;
    if (scale != 1) { sx = px / scale; sy = py / scale; }
    bool fov = (m != 0);
    int  fi  = fov ? (sy * WW + sx) : 0;       // masked lanes read row 0 (broadcast)
    float d  = fov ? depth[py * WW + px] : 0.0f;
    float diff = z - d;
    float gw = __expf(-0.5f * diff * diff);
    float w  = (d == 0.0f) ? 1.0f : gw;
    w = fov ? w : 0.0f;

    vint2 o; o.x = fi; o.y = __float_as_int(w);
    __builtin_nontemporal_store(o, meta + i);
}

// ---------------- Kernel 2: transpose+cvt x2d (C,HW) f32 -> xTs (S, HW, 8ch) fp16 -------
// Slice-major layout so each 128B line holds 8 pixels x 8ch of ONE slice:
// per-slice random working set = 4.9 MB (L2-resident), not 39 MB.
__global__ __launch_bounds__(256) void transpose_slice_kernel(
    const float* __restrict__ x2d,   // (C, HWTOT) f32
    _Float16*    __restrict__ xTs)   // (SLICES, HWTOT, CPS) fp16
{
    __shared__ float tile[64][65];   // pitch 65: worst 2-way bank aliasing (free)
    int t  = threadIdx.x;
    int p0 = blockIdx.x * 64;

#pragma unroll
    for (int k = 0; k < 4; ++k) {
        int idx = k * 256 + t;
        int c   = idx >> 4;          // 0..63 channel
        int pg  = idx & 15;          // float4 group within 64-pixel tile
        vfloat4 v = __builtin_nontemporal_load(
            (const vfloat4*)(x2d + (long)c * HWTOT + p0) + pg);
        tile[c][pg*4+0] = v.x;
        tile[c][pg*4+1] = v.y;
        tile[c][pg*4+2] = v.z;
        tile[c][pg*4+3] = v.w;
    }
    __syncthreads();
#pragma unroll
    for (int k = 0; k < 4; ++k) {
        int idx = k * 256 + t;
        int p   = idx >> 4;          // 0..63 pixel within tile
        int cg  = idx & 15;          // f16x4 channel group: channels 4cg..4cg+3
        f16x4 h;
        h[0] = (_Float16)tile[cg*4+0][p];
        h[1] = (_Float16)tile[cg*4+1][p];
        h[2] = (_Float16)tile[cg*4+2][p];
        h[3] = (_Float16)tile[cg*4+3][p];
        int s  = cg >> 1;            // slice
        int j0 = (cg & 1) * 4;       // half-row within slice
        *(f16x4*)(xTs + ((long)s * HWTOT + (p0 + p)) * CPS + j0) = h;
    }
}

// ---------------- Kernel 3: sliced gather — random reads hit L2-resident slice ----------
// grid = (NVOX/256, SLICES); x-major dispatch => one slice globally active at a time.
// meta/out are NONTEMPORAL (don't evict the slice); payload load is NORMAL (cache it).
__global__ __launch_bounds__(256) void gather_slice_kernel(
    const _Float16* __restrict__ xTs,   // (SLICES, HWTOT, CPS) fp16
    const vint2*    __restrict__ meta,  // (N,) {fi, bits(w)}
    float*          __restrict__ out)   // (C, N) f32
{
    int i = blockIdx.x * blockDim.x + threadIdx.x;   // voxel
    int s = blockIdx.y;                              // slice

    vint2 mw = __builtin_nontemporal_load(meta + i);
    int   fi = mw.x;
    float w  = __int_as_float(mw.y);

    f16x8 v = *(const f16x8*)(xTs + ((long)s * HWTOT + fi) * CPS);  // 16B, L2 hit
    float* op = out + (long)s * CPS * NVOX + i;

#pragma unroll
    for (int j = 0; j < CPS; ++j) {
        float f = (float)v[j] * w;                   // wave-instr: 256B contiguous
        __builtin_nontemporal_store(f, op + (long)j * NVOX);
    }
}

// ---------------- Fallback A (medium ws): R2 path, unsliced fp16 gather -----------------
__global__ __launch_bounds__(256) void transpose_f16_kernel(
    const float* __restrict__ x2d, _Float16* __restrict__ xT)
{
    __shared__ float tile[64][65];
    int t  = threadIdx.x;
    int p0 = blockIdx.x * 64;
#pragma unroll
    for (int k = 0; k < 4; ++k) {
        int idx = k * 256 + t;
        int c = idx >> 4, pg = idx & 15;
        vfloat4 v = __builtin_nontemporal_load(
            (const vfloat4*)(x2d + (long)c * HWTOT + p0) + pg);
        tile[c][pg*4+0] = v.x; tile[c][pg*4+1] = v.y;
        tile[c][pg*4+2] = v.z; tile[c][pg*4+3] = v.w;
    }
    __syncthreads();
#pragma unroll
    for (int k = 0; k < 4; ++k) {
        int idx = k * 256 + t;
        int p = idx >> 4, cg = idx & 15;
        f16x4 h;
        h[0] = (_Float16)tile[cg*4+0][p];
        h[1] = (_Float16)tile[cg*4+1][p];
        h[2] = (_Float16)tile[cg*4+2][p];
        h[3] = (_Float16)tile[cg*4+3][p];
        ((f16x4*)(xT + (long)(p0 + p) * CC))[cg] = h;
    }
}

__global__ __launch_bounds__(256) void gather_f16_kernel(
    const _Float16* __restrict__ xT, const vint2* __restrict__ meta,
    float* __restrict__ out)
{
    int i = blockIdx.x * blockDim.x + threadIdx.x;
    vint2 mw = __builtin_nontemporal_load(meta + i);
    int fi = mw.x; float w = __int_as_float(mw.y);
    const f16x8* src = (const f16x8*)(xT + (long)fi * CC);
    float* op = out + i;
    f16x8 s0 = src[0], s1 = src[1], s2 = src[2], s3 = src[3];
    f16x8 s4 = src[4], s5 = src[5], s6 = src[6], s7 = src[7];
    f16x8 ss[8] = {s0,s1,s2,s3,s4,s5,s6,s7};
#pragma unroll
    for (int g = 0; g < 8; ++g)
#pragma unroll
        for (int j = 0; j < 8; ++j)
            __builtin_nontemporal_store((float)ss[g][j] * w,
                                        op + (long)(8*g + j) * NVOX);
}

// ---------------- Fallback B (tiny ws): fully fused f32 --------------------------------
__global__ __launch_bounds__(256) void fused_kernel(
    const float* __restrict__ x2d, const int* __restrict__ pp,
    const int* __restrict__ scale_p, const int* __restrict__ mask,
    const float* __restrict__ pix_z, const float* __restrict__ depth,
    float* __restrict__ out)
{
    int t = blockIdx.x * blockDim.x + threadIdx.x;
    long i0 = (long)t * 4;
    int cg = blockIdx.y * 4;
    int scale = scale_p[0];

    vint4 pp0 = ((const vint4*)pp)[t*2+0];
    vint4 pp1 = ((const vint4*)pp)[t*2+1];
    vint4 m4  = ((const vint4*)mask)[t];
    vfloat4 z4 = ((const vfloat4*)pix_z)[t];

    int   px[4] = {pp0.x, pp0.z, pp1.x, pp1.z};
    int   py[4] = {pp0.y, pp0.w, pp1.y, pp1.w};
    int   mm[4] = {m4.x, m4.y, m4.z, m4.w};
    float zz[4] = {z4.x, z4.y, z4.z, z4.w};

    int fi[4]; float wv[4];
#pragma unroll
    for (int j = 0; j < 4; ++j) {
        int sx = px[j], sy = py[j];
        if (scale != 1) { sx = px[j] / scale; sy = py[j] / scale; }
        int feat = sy * WW + sx;
        bool fov = (mm[j] != 0);
        float d = fov ? depth[py[j] * WW + px[j]] : 0.0f;
        float diff = zz[j] - d;
        float gw = __expf(-0.5f * diff * diff);
        float w = (d == 0.0f) ? 1.0f : gw;
        wv[j] = fov ? w : 0.0f;
        fi[j] = fov ? feat : 0;
    }

#pragma unroll
    for (int g = 0; g < 4; ++g) {
        int c = cg + g;
        const float* base = x2d + (long)c * HWTOT;
        vfloat4 v;
        v.x = base[fi[0]] * wv[0];
        v.y = base[fi[1]] * wv[1];
        v.z = base[fi[2]] * wv[2];
        v.w = base[fi[3]] * wv[3];
        __builtin_nontemporal_store(v, (vfloat4*)(out + (long)c * NVOX + i0));
    }
}

extern "C" void kernel_launch(void* const* d_in, const int* in_sizes, int n_in,
                              void* d_out, int out_size, void* d_ws, size_t ws_size,
                              hipStream_t stream) {
    const float* x2d     = (const float*)d_in[0];
    const int*   pp      = (const int*)d_in[1];
    const int*   scale_p = (const int*)d_in[2];
    const int*   mask    = (const int*)d_in[3];
    const float* pix_z   = (const float*)d_in[4];
    const float* depth   = (const float*)d_in[5];
    float*       out     = (float*)d_out;

    dim3 blk(256);
    size_t meta_bytes = (size_t)NVOX * 8;                       // 16.8 MB
    size_t xT_bytes   = (size_t)HWTOT * CC * sizeof(_Float16);  // 39.3 MB
    size_t need_full  = meta_bytes + xT_bytes;                  // 56.1 MB

    if (ws_size >= need_full) {
        vint2*    meta = (vint2*)d_ws;
        _Float16* xTs  = (_Float16*)((char*)d_ws + meta_bytes);
        weight_kernel<<<dim3(NVOX/256), blk, 0, stream>>>(pp, scale_p, mask,
                                                          pix_z, depth, meta);
        transpose_slice_kernel<<<dim3(HWTOT/64), blk, 0, stream>>>(x2d, xTs);
        gather_slice_kernel<<<dim3(NVOX/256, SLICES), blk, 0, stream>>>(xTs, meta, out);
    } else if (ws_size >= xT_bytes + meta_bytes) {
        vint2*    meta = (vint2*)d_ws;
        _Float16* xT   = (_Float16*)((char*)d_ws + meta_bytes);
        weight_kernel<<<dim3(NVOX/256), blk, 0, stream>>>(pp, scale_p, mask,
                                                          pix_z, depth, meta);
        transpose_f16_kernel<<<dim3(HWTOT/64), blk, 0, stream>>>(x2d, xT);
        gather_f16_kernel<<<dim3(NVOX/256), blk, 0, stream>>>(xT, meta, out);
    } else {
        fused_kernel<<<dim3(NVOX/4/256, CC/4), blk, 0, stream>>>(x2d, pp, scale_p,
                                                                 mask, pix_z, depth, out);
    }
}